// Round 1
// 224.492 us; speedup vs baseline: 1.0372x; 1.0372x over previous
//
#include <hip/hip_runtime.h>
#include <hip/hip_fp16.h>

// GAT regression: 2-layer GAT + linear head.
// R8: agg1/agg2 restructured around 64-edge "super-chunks":
//  - per-edge scalar work (epair load, als gather, LeakyReLU, exp, bounds mask)
//    is computed ONCE per edge (one edge per lane), not redundantly by every
//    lane of a channel-group (was 16x in agg1 / 8x in agg2). Weights + src ids
//    are distributed to FMA lanes via __shfl (ds_bpermute).
//  - H rows stored as f16 (was bf16): unpack+fma folds to v_fma_mix_f32 and
//    rounding error shrinks ~8x.
//  - 32-bit gather addressing; 1-deep software pipeline on H-row gathers.
// Requires N < 65536 (16-bit packing). N = 50000.

#define LEAKY(x) ((x) > 0.f ? (x) : 0.2f * (x))

__device__ inline unsigned h16pack(float a, float b) {
  union { __half h[2]; unsigned u; } cv;
  cv.h[0] = __float2half(a);
  cv.h[1] = __float2half(b);
  return cv.u;
}

// 8 f16 channels (one uint4) * weight -> 8 f32 accumulators (v_fma_mix_f32)
__device__ inline void fma8h(uint4 v, float w, float& a0, float& a1, float& a2, float& a3,
                             float& a4, float& a5, float& a6, float& a7) {
  union { uint4 u; __half2 h[4]; } cv;
  cv.u = v;
  a0 = fmaf(__low2float(cv.h[0]), w, a0);
  a1 = fmaf(__high2float(cv.h[0]), w, a1);
  a2 = fmaf(__low2float(cv.h[1]), w, a2);
  a3 = fmaf(__high2float(cv.h[1]), w, a3);
  a4 = fmaf(__low2float(cv.h[2]), w, a4);
  a5 = fmaf(__high2float(cv.h[2]), w, a5);
  a6 = fmaf(__low2float(cv.h[3]), w, a6);
  a7 = fmaf(__high2float(cv.h[3]), w, a7);
}

// ---------------- bucketed CSR build ----------------

template <int VPT>
__global__ __launch_bounds__(256) void bucket_cnt_kernel(const int* __restrict__ ei, int E, int n,
                                                         int* __restrict__ bc) {
  __shared__ int lc[256];
  int t = threadIdx.x;
  lc[t] = 0;
  __syncthreads();
  int base = blockIdx.x * (256 * VPT) + t;
  int tot = E + n;
#pragma unroll
  for (int u = 0; u < VPT; ++u) {
    int i = base + u * 256;
    if (i < tot) {
      int d = (i < E) ? ei[E + i] : (i - E);
      atomicAdd(&lc[d >> 8], 1);
    }
  }
  __syncthreads();
  if (lc[t]) atomicAdd(&bc[t], lc[t]);
}

__global__ __launch_bounds__(256) void bucket_scan_kernel(const int* __restrict__ bc,
                                                          int* __restrict__ boff,
                                                          int* __restrict__ bcur, int B,
                                                          int* __restrict__ off, int n, int Etot) {
  __shared__ int sm[256];
  int t = threadIdx.x;
  int v = (t < B) ? bc[t] : 0;
  sm[t] = v;
  __syncthreads();
  for (int s = 1; s < 256; s <<= 1) {
    int a = (t >= s) ? sm[t - s] : 0;
    __syncthreads();
    sm[t] += a;
    __syncthreads();
  }
  int excl = sm[t] - v;
  if (t < B) { boff[t] = excl; bcur[t] = excl; }
  if (t == 0) { boff[B] = Etot; off[n] = Etot; }
}

template <int VPT>
__global__ __launch_bounds__(256) void bucket_scatter_kernel(const int* __restrict__ ei, int E,
                                                             int n, int* __restrict__ bcur,
                                                             unsigned* __restrict__ entries) {
  __shared__ int lc[256];
  __shared__ int lbase[256];
  int t = threadIdx.x;
  lc[t] = 0;
  __syncthreads();
  int base = blockIdx.x * (256 * VPT) + t;
  int tot = E + n;
  int bb[VPT], ll[VPT];
  unsigned pk[VPT];
#pragma unroll
  for (int u = 0; u < VPT; ++u) {
    int i = base + u * 256;
    bb[u] = -1;
    if (i < tot) {
      int s, d;
      if (i < E) { s = ei[i]; d = ei[E + i]; }
      else       { s = d = i - E; }
      int b = d >> 8;
      bb[u] = b;
      ll[u] = atomicAdd(&lc[b], 1);
      pk[u] = (unsigned)s | ((unsigned)(d & 255) << 16);
    }
  }
  __syncthreads();
  if (lc[t]) lbase[t] = atomicAdd(&bcur[t], lc[t]);
  __syncthreads();
#pragma unroll
  for (int u = 0; u < VPT; ++u)
    if (bb[u] >= 0) entries[lbase[bb[u]] + ll[u]] = pk[u];
}

__global__ __launch_bounds__(256) void csr_build_kernel(const unsigned* __restrict__ entries,
                                                        const int* __restrict__ boff,
                                                        int* __restrict__ off,
                                                        unsigned* __restrict__ epair, int n) {
  __shared__ int hist[256];
  __shared__ int scn[256];
  __shared__ int cur[256];
  int b = blockIdx.x, t = threadIdx.x;
  int k0 = boff[b], k1 = boff[b + 1];
  hist[t] = 0;
  __syncthreads();
  for (int k = k0 + t; k < k1; k += 256) atomicAdd(&hist[(entries[k] >> 16) & 255], 1);
  __syncthreads();
  int v = hist[t];
  scn[t] = v;
  __syncthreads();
  for (int s = 1; s < 256; s <<= 1) {
    int a = (t >= s) ? scn[t - s] : 0;
    __syncthreads();
    scn[t] += a;
    __syncthreads();
  }
  int excl = scn[t] - v;
  int d = (b << 8) + t;
  if (d < n) off[d] = k0 + excl;
  cur[t] = k0 + excl;
  __syncthreads();
  unsigned dbase = (unsigned)(b << 8) << 16;
  for (int k = k0 + t; k < k1; k += 256) {
    unsigned e = entries[k];
    unsigned dl = (e >> 16) & 255;
    int p = atomicAdd(&cur[dl], 1);
    epair[p] = (e & 0xffffu) | (dbase + (dl << 16));
  }
}

// ---------------- fused GEMM + logits (W via L1/L2, X tile in LDS) -----------

template <int K, int M, int NODES, int HEADS>
__global__ __launch_bounds__(256) void gemm_logits_kernel(const float* __restrict__ X,
                                                          const float* __restrict__ W,
                                                          const float* __restrict__ a_src,
                                                          const float* __restrict__ a_dst,
                                                          unsigned short* __restrict__ Hb,
                                                          float2* __restrict__ als,
                                                          float2* __restrict__ ald, int n) {
  constexpr int JPER = 4;
  constexpr int NSLOT = M / JPER;
  constexpr int SLOTS = 256 / NSLOT;
  constexpr int PER = NODES / SLOTS;
  __shared__ float Xl[NODES * K];

  int t = threadIdx.x;
  int nb0 = blockIdx.x * NODES;

  for (int i = t; i < NODES * K / 4; i += 256) {
    int r = i / (K / 4);
    int c = i % (K / 4);
    int node = nb0 + r;
    int nc = node < n ? node : (n - 1);
    ((float4*)Xl)[i] = ((const float4*)(X + (size_t)nc * K))[c];
  }
  __syncthreads();

  int j0 = (t % NSLOT) * JPER;
  int slot = t / NSLOT;
  const float4* Wg = (const float4*)W;

  float4 Asv = *(const float4*)(a_src + j0);
  float4 Adv = *(const float4*)(a_dst + j0);

  float acc[PER][JPER];
#pragma unroll
  for (int s = 0; s < PER; ++s)
#pragma unroll
    for (int q = 0; q < JPER; ++q) acc[s][q] = 0.f;

  for (int k4 = 0; k4 < K / 4; ++k4) {
    float4 w0 = Wg[(k4 * 4 + 0) * (M / 4) + (j0 >> 2)];
    float4 w1 = Wg[(k4 * 4 + 1) * (M / 4) + (j0 >> 2)];
    float4 w2 = Wg[(k4 * 4 + 2) * (M / 4) + (j0 >> 2)];
    float4 w3 = Wg[(k4 * 4 + 3) * (M / 4) + (j0 >> 2)];
#pragma unroll
    for (int s = 0; s < PER; ++s) {
      float4 xv = ((const float4*)Xl)[(slot * PER + s) * (K / 4) + k4];
      acc[s][0] += xv.x * w0.x + xv.y * w1.x + xv.z * w2.x + xv.w * w3.x;
      acc[s][1] += xv.x * w0.y + xv.y * w1.y + xv.z * w2.y + xv.w * w3.y;
      acc[s][2] += xv.x * w0.z + xv.y * w1.z + xv.z * w2.z + xv.w * w3.z;
      acc[s][3] += xv.x * w0.w + xv.y * w1.w + xv.z * w2.w + xv.w * w3.w;
    }
  }

#pragma unroll
  for (int s = 0; s < PER; ++s) {
    int node = nb0 + slot * PER + s;
    if (node < n) {
      uint2 b;
      b.x = h16pack(acc[s][0], acc[s][1]);
      b.y = h16pack(acc[s][2], acc[s][3]);
      *(uint2*)(Hb + (size_t)node * M + j0) = b;
    }
    float ps = acc[s][0] * Asv.x + acc[s][1] * Asv.y + acc[s][2] * Asv.z + acc[s][3] * Asv.w;
    float pd = acc[s][0] * Adv.x + acc[s][1] * Adv.y + acc[s][2] * Adv.z + acc[s][3] * Adv.w;
#pragma unroll
    for (int m = 1; m <= 8; m <<= 1) {
      ps += __shfl_xor(ps, m, 64);
      pd += __shfl_xor(pd, m, 64);
    }
    if (HEADS == 2) {
      float ps_o = __shfl_xor(ps, 16, 64);
      float pd_o = __shfl_xor(pd, 16, 64);
      if ((t & 31) == 0 && node < n) {
        als[node] = make_float2(ps, ps_o);
        ald[node] = make_float2(pd, pd_o);
      }
    } else {
      if ((t & 15) == 0 && node < n) als[node] = make_float2(ps, pd);
    }
  }
}

// ---------------- aggregation: super-chunk (64 edges), per-edge work once ----

// layer 1: 16 lanes/row (uint4); weights computed one-edge-per-lane, shfl'd to
// FMA lanes; f16 rows consumed via v_fma_mix; 1-deep gather pipeline.
__global__ __launch_bounds__(256) void agg1_kernel(const unsigned short* __restrict__ Hb,
                                                   const float2* __restrict__ als,
                                                   const float2* __restrict__ ald,
                                                   const unsigned* __restrict__ epair,
                                                   const int* __restrict__ off,
                                                   const float* __restrict__ b1,
                                                   float* __restrict__ O, int n) {
  int wid = (blockIdx.x * 256 + threadIdx.x) >> 6;
  int lane = threadIdx.x & 63;
  if (wid >= n) return;
  int q = lane >> 4;   // edge slot 0..3 within a sub-chunk of 8
  int c = lane & 15;   // channel group: ch 8c..8c+7
  int hd = c >> 3;     // head of these channels
  int k0 = off[wid], k1 = off[wid + 1];
  const uint4* Hq = (const uint4*)Hb;  // row = 16 uint4
  float2 advv = ald[wid];

  float a0 = 0.f, a1 = 0.f, a2 = 0.f, a3 = 0.f;
  float a4 = 0.f, a5 = 0.f, a6 = 0.f, a7 = 0.f;
  float den0 = 0.f, den1 = 0.f;

  for (int kb = k0; kb < k1; kb += 64) {
    // ---- weight phase: ONE edge per lane ----
    int e = kb + lane;
    bool ok = e < k1;
    unsigned pp = epair[ok ? e : k0];       // deg >= 1 (self-loop) so k0 valid
    float2 l = als[pp & 0xffffu];
    float x0 = l.x + advv.x;
    float x1 = l.y + advv.y;
    x0 = LEAKY(x0);
    x1 = LEAKY(x1);
    float g0 = ok ? __expf(x0) : 0.f;       // head-0 weight of edge e
    float g1 = ok ? __expf(x1) : 0.f;       // head-1 weight of edge e
    den0 += g0;
    den1 += g1;

    int nsub = (min(k1 - kb, 64) + 7) >> 3;  // sub-chunks of 8 edges

    uint4 vA0, vA1, vB0 = {0, 0, 0, 0}, vB1 = {0, 0, 0, 0};
    float wA0, wA1, wB0 = 0.f, wB1 = 0.f;
    auto issue = [&](int s, uint4& v0, uint4& v1, float& w0, float& w1) {
      int i0 = (s << 3) + q, i1 = i0 + 4;
      unsigned p0 = __shfl(pp, i0, 64);
      unsigned p1 = __shfl(pp, i1, 64);
      float h00 = __shfl(g0, i0, 64);
      float h10 = __shfl(g1, i0, 64);
      float h01 = __shfl(g0, i1, 64);
      float h11 = __shfl(g1, i1, 64);
      w0 = hd ? h10 : h00;
      w1 = hd ? h11 : h01;
      v0 = Hq[((p0 & 0xffffu) << 4) + (unsigned)c];
      v1 = Hq[((p1 & 0xffffu) << 4) + (unsigned)c];
    };
    issue(0, vA0, vA1, wA0, wA1);
    for (int s = 0; s < nsub; ++s) {
      if (s + 1 < nsub) issue(s + 1, vB0, vB1, wB0, wB1);
      fma8h(vA0, wA0, a0, a1, a2, a3, a4, a5, a6, a7);
      fma8h(vA1, wA1, a0, a1, a2, a3, a4, a5, a6, a7);
      vA0 = vB0; vA1 = vB1; wA0 = wB0; wA1 = wB1;
    }
  }

  // den: full 64-lane butterfly (per-lane contributions are distinct edges)
#pragma unroll
  for (int m = 1; m <= 32; m <<= 1) {
    den0 += __shfl_xor(den0, m, 64);
    den1 += __shfl_xor(den1, m, 64);
  }
  // accumulators: reduce across the 4 edge slots (lane bits 4,5)
#pragma unroll
  for (int m = 16; m <= 32; m <<= 1) {
    a0 += __shfl_xor(a0, m, 64);
    a1 += __shfl_xor(a1, m, 64);
    a2 += __shfl_xor(a2, m, 64);
    a3 += __shfl_xor(a3, m, 64);
    a4 += __shfl_xor(a4, m, 64);
    a5 += __shfl_xor(a5, m, 64);
    a6 += __shfl_xor(a6, m, 64);
    a7 += __shfl_xor(a7, m, 64);
  }
  if (q == 0) {
    float den = hd ? den1 : den0;
    float inv = 1.f / (den + 1e-16f);
    float4 bv0 = ((const float4*)b1)[2 * c];
    float4 bv1 = ((const float4*)b1)[2 * c + 1];
    float4 r0, r1;
    r0.x = a0 * inv + bv0.x;
    r0.y = a1 * inv + bv0.y;
    r0.z = a2 * inv + bv0.z;
    r0.w = a3 * inv + bv0.w;
    r1.x = a4 * inv + bv1.x;
    r1.y = a5 * inv + bv1.y;
    r1.z = a6 * inv + bv1.z;
    r1.w = a7 * inv + bv1.w;
    r0.x = r0.x > 0.f ? r0.x : (__expf(r0.x) - 1.f);
    r0.y = r0.y > 0.f ? r0.y : (__expf(r0.y) - 1.f);
    r0.z = r0.z > 0.f ? r0.z : (__expf(r0.z) - 1.f);
    r0.w = r0.w > 0.f ? r0.w : (__expf(r0.w) - 1.f);
    r1.x = r1.x > 0.f ? r1.x : (__expf(r1.x) - 1.f);
    r1.y = r1.y > 0.f ? r1.y : (__expf(r1.y) - 1.f);
    r1.z = r1.z > 0.f ? r1.z : (__expf(r1.z) - 1.f);
    r1.w = r1.w > 0.f ? r1.w : (__expf(r1.w) - 1.f);
    float4* Orow = (float4*)(O + ((size_t)wid << 7));
    Orow[2 * c] = r0;
    Orow[2 * c + 1] = r1;
  }
}

// layer 2 + head: 8 lanes/row (uint4); sub-chunks of 16 edges; same scheme.
__global__ __launch_bounds__(256) void agg2_kernel(const unsigned short* __restrict__ Hb2,
                                                   const float2* __restrict__ al2,
                                                   const unsigned* __restrict__ epair,
                                                   const int* __restrict__ off,
                                                   const float* __restrict__ b2,
                                                   const float* __restrict__ lin_w,
                                                   const float* __restrict__ lin_b,
                                                   float* __restrict__ out, int n) {
  int wid = (blockIdx.x * 256 + threadIdx.x) >> 6;
  int lane = threadIdx.x & 63;
  if (wid >= n) return;
  int q = lane >> 3;   // edge slot 0..7 within a sub-chunk of 16
  int c = lane & 7;    // channel group: ch 8c..8c+7
  int k0 = off[wid], k1 = off[wid + 1];
  const uint4* Hq = (const uint4*)Hb2;  // row = 8 uint4
  float adv = al2[wid].y;

  float a0 = 0.f, a1 = 0.f, a2 = 0.f, a3 = 0.f;
  float a4 = 0.f, a5 = 0.f, a6 = 0.f, a7 = 0.f;
  float den = 0.f;

  for (int kb = k0; kb < k1; kb += 64) {
    // ---- weight phase: ONE edge per lane ----
    int e = kb + lane;
    bool ok = e < k1;
    unsigned pp = epair[ok ? e : k0];
    float x = al2[pp & 0xffffu].x + adv;
    x = LEAKY(x);
    float g = ok ? __expf(x) : 0.f;
    den += g;

    int nsub = (min(k1 - kb, 64) + 15) >> 4;  // sub-chunks of 16 edges

    uint4 vA0, vA1, vB0 = {0, 0, 0, 0}, vB1 = {0, 0, 0, 0};
    float wA0, wA1, wB0 = 0.f, wB1 = 0.f;
    auto issue = [&](int s, uint4& v0, uint4& v1, float& w0, float& w1) {
      int i0 = (s << 4) + q, i1 = i0 + 8;
      unsigned p0 = __shfl(pp, i0, 64);
      unsigned p1 = __shfl(pp, i1, 64);
      w0 = __shfl(g, i0, 64);
      w1 = __shfl(g, i1, 64);
      v0 = Hq[((p0 & 0xffffu) << 3) + (unsigned)c];
      v1 = Hq[((p1 & 0xffffu) << 3) + (unsigned)c];
    };
    issue(0, vA0, vA1, wA0, wA1);
    for (int s = 0; s < nsub; ++s) {
      if (s + 1 < nsub) issue(s + 1, vB0, vB1, wB0, wB1);
      fma8h(vA0, wA0, a0, a1, a2, a3, a4, a5, a6, a7);
      fma8h(vA1, wA1, a0, a1, a2, a3, a4, a5, a6, a7);
      vA0 = vB0; vA1 = vB1; wA0 = wB0; wA1 = wB1;
    }
  }

  // den: full 64-lane butterfly
#pragma unroll
  for (int m = 1; m <= 32; m <<= 1) den += __shfl_xor(den, m, 64);
  // accumulators: reduce across the 8 edge slots (lane bits 3,4,5)
#pragma unroll
  for (int m = 8; m <= 32; m <<= 1) {
    a0 += __shfl_xor(a0, m, 64);
    a1 += __shfl_xor(a1, m, 64);
    a2 += __shfl_xor(a2, m, 64);
    a3 += __shfl_xor(a3, m, 64);
    a4 += __shfl_xor(a4, m, 64);
    a5 += __shfl_xor(a5, m, 64);
    a6 += __shfl_xor(a6, m, 64);
    a7 += __shfl_xor(a7, m, 64);
  }
  float inv = 1.f / (den + 1e-16f);
  float4 bv0 = ((const float4*)b2)[2 * c];
  float4 bv1 = ((const float4*)b2)[2 * c + 1];
  float4 lv0 = ((const float4*)lin_w)[2 * c];
  float4 lv1 = ((const float4*)lin_w)[2 * c + 1];
  float p = (a0 * inv + bv0.x) * lv0.x + (a1 * inv + bv0.y) * lv0.y +
            (a2 * inv + bv0.z) * lv0.z + (a3 * inv + bv0.w) * lv0.w +
            (a4 * inv + bv1.x) * lv1.x + (a5 * inv + bv1.y) * lv1.y +
            (a6 * inv + bv1.z) * lv1.z + (a7 * inv + bv1.w) * lv1.w;
#pragma unroll
  for (int m = 1; m <= 4; m <<= 1) p += __shfl_xor(p, m, 64);
  if (lane == 0) out[wid] = p + lin_b[0];
}

// ---------------- launcher ----------------

static inline size_t alignup(size_t v) { return (v + 255) & ~(size_t)255; }

extern "C" void kernel_launch(void* const* d_in, const int* in_sizes, int n_in,
                              void* d_out, int out_size, void* d_ws, size_t ws_size,
                              hipStream_t stream) {
  const float* x   = (const float*)d_in[0];
  const int*   ei  = (const int*)d_in[1];
  const float* W1  = (const float*)d_in[2];
  const float* as1 = (const float*)d_in[3];
  const float* ad1 = (const float*)d_in[4];
  const float* b1  = (const float*)d_in[5];
  const float* W2  = (const float*)d_in[6];
  const float* as2 = (const float*)d_in[7];
  const float* ad2 = (const float*)d_in[8];
  const float* b2  = (const float*)d_in[9];
  const float* lw  = (const float*)d_in[10];
  const float* lb  = (const float*)d_in[11];
  float* out = (float*)d_out;

  const int N = out_size;          // 50000
  const int E = in_sizes[1] / 2;   // 1600000
  const int Etot = E + N;
  const int B = (N + 255) >> 8;    // 196 buckets

  char* p = (char*)d_ws;
  int* bcnt = (int*)p;  p += alignup((size_t)(B + 1) * 4);
  int* boff = (int*)p;  p += alignup((size_t)(B + 1) * 4);
  int* bcur = (int*)p;  p += alignup((size_t)B * 4);
  unsigned* entries = (unsigned*)p; p += alignup((size_t)Etot * 4);
  int* off  = (int*)p;  p += alignup((size_t)(N + 1) * 4);
  unsigned* epair = (unsigned*)p; p += alignup((size_t)Etot * 4);
  float2* als = (float2*)p; p += alignup((size_t)N * 8);
  float2* ald = (float2*)p; p += alignup((size_t)N * 8);
  float2* al2 = (float2*)p; p += alignup((size_t)N * 8);
  float* h1a  = (float*)p; p += alignup((size_t)N * 128 * 4);
  unsigned short* h1b = (unsigned short*)p; p += alignup((size_t)N * 128 * 2);
  unsigned short* h2b = (unsigned short*)p; p += alignup((size_t)N * 64 * 2);

  hipMemsetAsync(bcnt, 0, (size_t)(B + 1) * sizeof(int), stream);

  constexpr int VPT = 8;
  int egrid = (Etot + 256 * VPT - 1) / (256 * VPT);

  bucket_cnt_kernel<VPT><<<egrid, 256, 0, stream>>>(ei, E, N, bcnt);
  bucket_scan_kernel<<<1, 256, 0, stream>>>(bcnt, boff, bcur, B, off, N, Etot);
  bucket_scatter_kernel<VPT><<<egrid, 256, 0, stream>>>(ei, E, N, bcur, entries);
  csr_build_kernel<<<B, 256, 0, stream>>>(entries, boff, off, epair, N);

  gemm_logits_kernel<128, 128, 32, 2>
      <<<(N + 31) / 32, 256, 0, stream>>>(x, W1, as1, ad1, h1b, als, ald, N);
  agg1_kernel<<<(N + 3) / 4, 256, 0, stream>>>(h1b, als, ald, epair, off, b1, h1a, N);

  gemm_logits_kernel<128, 64, 64, 1>
      <<<(N + 63) / 64, 256, 0, stream>>>(h1a, W2, as2, ad2, h2b, al2, nullptr, N);
  agg2_kernel<<<(N + 3) / 4, 256, 0, stream>>>(h2b, al2, epair, off, b2, lw, lb, out, N);
}